// Round 9
// baseline (94.736 us; speedup 1.0000x reference)
//
#include <hip/hip_runtime.h>

#define N_BOXES 4194304
#define BCE_COEFF 0.2f
#define BLOCK 256
#define WAVES 4
#define WCHUNK 64                            // boxes per wave-chunk (1 box/lane)
#define F4_IN (WCHUNK * 5 / 4)               // 80 float4 per input per chunk
#define F4_TOT (F4_IN * 2)                   // 160 float4 (preds + target)
#define NBLOCKS 2048                         // persistent, exactly 8 blocks/CU
#define BOXES_PER_WAVE (N_BOXES / NBLOCKS / WAVES)   // 512
#define ROUNDS (BOXES_PER_WAVE / WCHUNK)             // 8
#define POISON 0xAAAAAAAAu

// Async global->LDS DMA, 16 B/lane; linear dest = wave-uniform base + lane*16.
__device__ __forceinline__ void g2lds16(const float4* g, float4* l) {
    __builtin_amdgcn_global_load_lds(
        (const __attribute__((address_space(1))) void*)g,
        (__attribute__((address_space(3))) void*)l,
        16, 0, 0);
}

__global__ __launch_bounds__(BLOCK, 8) void eiou_main(
        const float* __restrict__ preds,
        const float* __restrict__ target,
        float* __restrict__ slots,
        unsigned* __restrict__ counter,
        float* __restrict__ out) {
    // Wave-private double buffers: 4 waves x 2 bufs x 160 float4 = 20480 B
    // -> exactly 8 blocks/CU (160 KB LDS), 32 waves/CU.
    __shared__ float4 sbuf[WAVES][2][F4_TOT];
    __shared__ bool sIsLast;

    const int t    = threadIdx.x;
    const int lane = t & 63;
    const int w    = t >> 6;
    const float4* const p4 = reinterpret_cast<const float4*>(preds);
    const float4* const t4 = reinterpret_cast<const float4*>(target);

    // Per-input float4 base for this wave: block*2560 + wave*640.
    const size_t wbase = (size_t)blockIdx.x * (N_BOXES / NBLOCKS * 5 / 4)
                       + (size_t)w * (BOXES_PER_WAVE * 5 / 4);

    // Stage one 64-box wave-chunk (2.5 KB): 3 DMA instrs (last half-masked).
    auto stage = [&](int c, int b) {
        const size_t fb = wbase + (size_t)c * F4_IN;
#pragma unroll
        for (int k = 0; k < 3; ++k) {
            const int q = k * 64 + lane;                 // 0..191
            if (q < F4_TOT) {
                const float4* src = (q < F4_IN) ? (p4 + fb + q)
                                                : (t4 + fb + (q - F4_IN));
                g2lds16(src, &sbuf[w][b][q]);
            }
        }
    };

    stage(0, 0);                     // prologue
    float acc = 0.0f;

    // ---- barrier-free per-wave double-buffered pipeline ----
    for (int c = 0; c < ROUNDS; ++c) {
        const int b = c & 1;
        if (c + 1 < ROUNDS) {
            asm volatile("s_waitcnt lgkmcnt(0)" ::: "memory");  // prior buf reads retired
            stage(c + 1, b ^ 1);                                // in flight under compute
            asm volatile("s_waitcnt vmcnt(3)" ::: "memory");    // chunk c landed
        } else {
            asm volatile("s_waitcnt vmcnt(0)" ::: "memory");
        }

        const float* __restrict__ s = reinterpret_cast<const float*>(&sbuf[w][b][0]);
        const float* __restrict__ P = s + lane * 5;
        const float* __restrict__ T = s + WCHUNK * 5 + lane * 5;

        const float x = P[0];
        const float y = T[0];
        const float p0 = __fdividef(1.0f, 1.0f + __expf(-P[1]));
        const float p1 = __fdividef(1.0f, 1.0f + __expf(-P[2]));
        const float p2 = __fdividef(1.0f, 1.0f + __expf(-P[3]));
        const float p3 = __fdividef(1.0f, 1.0f + __expf(-P[4]));
        const float t0 = T[1], t1 = T[2], t2 = T[3], t3 = T[4];

        const float xp1 = fminf(p2, p0), xp2 = fmaxf(p2, p0);
        const float yp1 = fminf(p1, p3), yp2 = fmaxf(p1, p3);

        const float wv = xp2 - xp1;        // == |p2-p0|
        const float h  = yp2 - yp1;        // == |p3-p1|
        const float wt = t2 - t0;
        const float ht = t3 - t1;
        const float pred_area   = wv * h;
        const float target_area = wt * ht;

        const float x1 = fmaxf(xp1, t0), x2 = fminf(xp2, t2);
        const float y1 = fmaxf(yp1, t1), y2 = fminf(yp2, t3);

        float ov = (x2 - x1) * (y2 - y1);
        ov = (ov < 0.0f) ? 0.0f : ov;

        const float x1c = fminf(xp1, t0), x2c = fmaxf(xp2, t2);
        const float y1c = fminf(yp1, t1), y2c = fmaxf(yp2, t3);

        const float cw = x2c - x1c, ch = y2c - y1c;

        const float iou = __fdividef(ov, target_area + pred_area - ov);

        const float dx = 0.5f * ((xp1 + xp2) - (t0 + t2));
        const float dy = 0.5f * ((yp1 + yp2) - (t1 + t3));
        const float diag = cw * cw + ch * ch;
        const float center_part = __fdividef(dx * dx + dy * dy, diag);

        // width_part + height_part with one reciprocal:
        // (dwv/cw)^2 + (dhv/ht)^2 = ((dwv*ht)^2 + (dhv*cw)^2) / (cw*ht)^2
        const float dwv = wv - wt, dhv = h - ht;
        const float a = dwv * ht, bb = dhv * cw, d = cw * ht;
        const float wh_part = __fdividef(a * a + bb * bb, d * d);

        const float eiou = 1.0f - (iou - (center_part + wh_part));

        const float bce = fmaxf(x, 0.0f) - x * y
                        + __logf(1.0f + __expf(-fabsf(x)));

        acc += BCE_COEFF * bce + eiou;
    }

    // ---- block reduction ----
#pragma unroll
    for (int off = 32; off > 0; off >>= 1)
        acc += __shfl_down(acc, off);

    __syncthreads();                 // all LDS pipeline reads done
    float* sf = reinterpret_cast<float*>(&sbuf[0][0][0]);
    if (lane == 0) sf[w] = acc;
    __syncthreads();

    // ---- publish partial; last block to finish does the final reduce ----
    if (t == 0) {
        const float bs = (sf[0] + sf[1]) + (sf[2] + sf[3]);
        // Heal counter poison (0xAA..) on the first call after a poison pass.
        atomicCAS(counter, POISON, 0u);
        atomicExch(&slots[blockIdx.x], bs);   // device-scope publish
        __threadfence();                       // slot visible before count
        const unsigned ret = atomicAdd(counter, 1u);
        sIsLast = (ret == NBLOCKS - 1);
    }
    __syncthreads();

    if (sIsLast) {
        __threadfence();                       // acquire all published slots
        float v = 0.0f;
#pragma unroll
        for (int k = 0; k < NBLOCKS / BLOCK; ++k)        // 8 independent reads
            v += atomicAdd(&slots[t + k * BLOCK], 0.0f); // device-scope read
#pragma unroll
        for (int off = 32; off > 0; off >>= 1)
            v += __shfl_down(v, off);

        __syncthreads();
        if (lane == 0) sf[w] = v;
        __syncthreads();
        if (t == 0) {
            atomicExch(counter, 0u);           // reset for next graph replay
            out[0] = ((sf[0] + sf[1]) + (sf[2] + sf[3]))
                   * (1.0f / (float)N_BOXES);
        }
    }
}

extern "C" void kernel_launch(void* const* d_in, const int* in_sizes, int n_in,
                              void* d_out, int out_size, void* d_ws, size_t ws_size,
                              hipStream_t stream) {
    const float* preds  = (const float*)d_in[0];
    const float* target = (const float*)d_in[1];
    float*    slots   = (float*)d_ws;                          // 2048 floats
    unsigned* counter = (unsigned*)((char*)d_ws + NBLOCKS * sizeof(float));
    float*    out     = (float*)d_out;

    // Single fused dispatch; counter self-heals from poison and self-resets.
    eiou_main<<<NBLOCKS, BLOCK, 0, stream>>>(preds, target, slots, counter, out);
}

// Round 10
// 48.531 us; speedup vs baseline: 1.9521x; 1.9521x over previous
//
#include <hip/hip_runtime.h>

#define N_BOXES 4194304
#define BCE_COEFF 0.2f
#define BLOCK 256
#define WAVES 4
#define WCHUNK 64                            // boxes per wave-chunk (1 box/lane)
#define F4_IN (WCHUNK * 5 / 4)               // 80 float4 per input per chunk
#define F4_TOT (F4_IN * 2)                   // 160 float4 (preds + target)
#define NBLOCKS 2048                         // exactly 8 blocks/CU, all resident
#define BOXES_PER_WAVE (N_BOXES / NBLOCKS / WAVES)   // 512
#define ROUNDS (BOXES_PER_WAVE / WCHUNK)             // 8

// Async global->LDS DMA, 16 B/lane; linear dest = wave-uniform base + lane*16.
__device__ __forceinline__ void g2lds16(const float4* g, float4* l) {
    __builtin_amdgcn_global_load_lds(
        (const __attribute__((address_space(1))) void*)g,
        (__attribute__((address_space(3))) void*)l,
        16, 0, 0);
}

__global__ __launch_bounds__(BLOCK, 8) void eiou_main(
        const float* __restrict__ preds,
        const float* __restrict__ target,
        float* __restrict__ out) {
    // Wave-private double buffers: 4 waves x 2 bufs x 160 float4 = 20480 B
    // -> exactly 8 blocks/CU (160 KB LDS), 32 waves/CU.
    __shared__ float4 sbuf[WAVES][2][F4_TOT];

    const int t    = threadIdx.x;
    const int lane = t & 63;
    const int w    = t >> 6;
    const float4* const p4 = reinterpret_cast<const float4*>(preds);
    const float4* const t4 = reinterpret_cast<const float4*>(target);

    // Per-input float4 base for this wave: block*2560 + wave*640.
    const size_t wbase = (size_t)blockIdx.x * (N_BOXES / NBLOCKS * 5 / 4)
                       + (size_t)w * (BOXES_PER_WAVE * 5 / 4);

    // Stage one 64-box wave-chunk (2.5 KB): 3 DMA instrs (last half-masked).
    auto stage = [&](int c, int b) {
        const size_t fb = wbase + (size_t)c * F4_IN;
#pragma unroll
        for (int k = 0; k < 3; ++k) {
            const int q = k * 64 + lane;                 // 0..191
            if (q < F4_TOT) {
                const float4* src = (q < F4_IN) ? (p4 + fb + q)
                                                : (t4 + fb + (q - F4_IN));
                g2lds16(src, &sbuf[w][b][q]);
            }
        }
    };

    stage(0, 0);                     // prologue
    float acc = 0.0f;

    // ---- barrier-free per-wave double-buffered pipeline ----
    for (int c = 0; c < ROUNDS; ++c) {
        const int b = c & 1;
        if (c + 1 < ROUNDS) {
            asm volatile("s_waitcnt lgkmcnt(0)" ::: "memory");  // prior buf reads retired
            stage(c + 1, b ^ 1);                                // in flight under compute
            asm volatile("s_waitcnt vmcnt(3)" ::: "memory");    // chunk c landed
        } else {
            asm volatile("s_waitcnt vmcnt(0)" ::: "memory");
        }

        const float* __restrict__ s = reinterpret_cast<const float*>(&sbuf[w][b][0]);
        const float* __restrict__ P = s + lane * 5;
        const float* __restrict__ T = s + WCHUNK * 5 + lane * 5;

        const float x = P[0];
        const float y = T[0];
        const float p0 = __fdividef(1.0f, 1.0f + __expf(-P[1]));
        const float p1 = __fdividef(1.0f, 1.0f + __expf(-P[2]));
        const float p2 = __fdividef(1.0f, 1.0f + __expf(-P[3]));
        const float p3 = __fdividef(1.0f, 1.0f + __expf(-P[4]));
        const float t0 = T[1], t1 = T[2], t2 = T[3], t3 = T[4];

        const float xp1 = fminf(p2, p0), xp2 = fmaxf(p2, p0);
        const float yp1 = fminf(p1, p3), yp2 = fmaxf(p1, p3);

        const float wv = xp2 - xp1;        // == |p2-p0|
        const float h  = yp2 - yp1;        // == |p3-p1|
        const float wt = t2 - t0;
        const float ht = t3 - t1;
        const float pred_area   = wv * h;
        const float target_area = wt * ht;

        const float x1 = fmaxf(xp1, t0), x2 = fminf(xp2, t2);
        const float y1 = fmaxf(yp1, t1), y2 = fminf(yp2, t3);

        float ov = (x2 - x1) * (y2 - y1);
        ov = (ov < 0.0f) ? 0.0f : ov;

        const float x1c = fminf(xp1, t0), x2c = fmaxf(xp2, t2);
        const float y1c = fminf(yp1, t1), y2c = fmaxf(yp2, t3);

        const float cw = x2c - x1c, ch = y2c - y1c;

        const float iou = __fdividef(ov, target_area + pred_area - ov);

        const float dx = 0.5f * ((xp1 + xp2) - (t0 + t2));
        const float dy = 0.5f * ((yp1 + yp2) - (t1 + t3));
        const float diag = cw * cw + ch * ch;
        const float center_part = __fdividef(dx * dx + dy * dy, diag);

        // width_part + height_part with one reciprocal:
        // (dwv/cw)^2 + (dhv/ht)^2 = ((dwv*ht)^2 + (dhv*cw)^2) / (cw*ht)^2
        const float dwv = wv - wt, dhv = h - ht;
        const float a = dwv * ht, bb = dhv * cw, d = cw * ht;
        const float wh_part = __fdividef(a * a + bb * bb, d * d);

        const float eiou = 1.0f - (iou - (center_part + wh_part));

        const float bce = fmaxf(x, 0.0f) - x * y
                        + __logf(1.0f + __expf(-fabsf(x)));

        acc += BCE_COEFF * bce + eiou;
    }

    // ---- block reduction ----
#pragma unroll
    for (int off = 32; off > 0; off >>= 1)
        acc += __shfl_down(acc, off);

    __syncthreads();                 // all LDS pipeline reads done
    float* sf = reinterpret_cast<float*>(&sbuf[0][0][0]);
    if (lane == 0) sf[w] = acc;
    __syncthreads();

    // One fire-and-forget device-scope atomic per block, pre-scaled.
    // NO fences (round-7/9 lesson: per-block __threadfence = L2 writeback
    // storm, +25..60 us; plain atomicAdd absorbed into finish skew, rounds 2/4).
    if (t == 0) {
        const float bs = (sf[0] + sf[1]) + (sf[2] + sf[3]);
        atomicAdd(out, bs * (1.0f / (float)N_BOXES));
    }
}

extern "C" void kernel_launch(void* const* d_in, const int* in_sizes, int n_in,
                              void* d_out, int out_size, void* d_ws, size_t ws_size,
                              hipStream_t stream) {
    const float* preds  = (const float*)d_in[0];
    const float* target = (const float*)d_in[1];
    float* out = (float*)d_out;

    // Zero the 4-byte accumulator (graph-capture-safe async memset node).
    hipMemsetAsync(out, 0, sizeof(float), stream);
    eiou_main<<<NBLOCKS, BLOCK, 0, stream>>>(preds, target, out);
}

// Round 11
// 32.989 us; speedup vs baseline: 2.8718x; 1.4711x over previous
//
#include <hip/hip_runtime.h>

#define N_BOXES 4194304
#define BCE_COEFF 0.2f
#define BLOCK 256
#define WAVES 4
#define WCHUNK 64                            // boxes per wave-chunk (1 box/lane)
#define F4_IN (WCHUNK * 5 / 4)               // 80 float4 per input per chunk
#define F4_TOT (F4_IN * 2)                   // 160 float4 (preds + target)
#define NBLOCKS 2048                         // exactly 8 blocks/CU, all resident
#define BOXES_PER_WAVE (N_BOXES / NBLOCKS / WAVES)   // 512
#define ROUNDS (BOXES_PER_WAVE / WCHUNK)             // 8
#define POISON 0xAAAAAAAAu

#define GROUPS 64                            // 2048 blocks -> 64 groups of 32
#define SLOT_STRIDE 32                       // 32 floats = 128 B: one line/slot
// d_ws layout (u32/float indices):
//   subslot[g]  : float @ g*32            (64 slots, line-padded)
//   subcnt[g]   : u32   @ 2048 + g*32     (64 counters, line-padded)
//   superslot   : float @ 4096
//   supercnt    : u32   @ 4128
#define SUBCNT_BASE 2048
#define SUPER_SLOT  4096
#define SUPER_CNT   4128

// Async global->LDS DMA, 16 B/lane; linear dest = wave-uniform base + lane*16.
__device__ __forceinline__ void g2lds16(const float4* g, float4* l) {
    __builtin_amdgcn_global_load_lds(
        (const __attribute__((address_space(1))) void*)g,
        (__attribute__((address_space(3))) void*)l,
        16, 0, 0);
}

__global__ __launch_bounds__(BLOCK, 8) void eiou_main(
        const float* __restrict__ preds,
        const float* __restrict__ target,
        float* __restrict__ wsf,
        float* __restrict__ out) {
    // Wave-private double buffers: 4 waves x 2 bufs x 160 float4 = 20480 B
    // -> exactly 8 blocks/CU (160 KB LDS), 32 waves/CU.
    __shared__ float4 sbuf[WAVES][2][F4_TOT];

    const int t    = threadIdx.x;
    const int lane = t & 63;
    const int w    = t >> 6;
    const float4* const p4 = reinterpret_cast<const float4*>(preds);
    const float4* const t4 = reinterpret_cast<const float4*>(target);

    // Per-input float4 base for this wave: block*2560 + wave*640.
    const size_t wbase = (size_t)blockIdx.x * (N_BOXES / NBLOCKS * 5 / 4)
                       + (size_t)w * (BOXES_PER_WAVE * 5 / 4);

    // Stage one 64-box wave-chunk (2.5 KB): 3 DMA instrs (last half-masked).
    auto stage = [&](int c, int b) {
        const size_t fb = wbase + (size_t)c * F4_IN;
#pragma unroll
        for (int k = 0; k < 3; ++k) {
            const int q = k * 64 + lane;                 // 0..191
            if (q < F4_TOT) {
                const float4* src = (q < F4_IN) ? (p4 + fb + q)
                                                : (t4 + fb + (q - F4_IN));
                g2lds16(src, &sbuf[w][b][q]);
            }
        }
    };

    stage(0, 0);                     // prologue
    float acc = 0.0f;

    // ---- barrier-free per-wave double-buffered pipeline ----
    for (int c = 0; c < ROUNDS; ++c) {
        const int b = c & 1;
        if (c + 1 < ROUNDS) {
            asm volatile("s_waitcnt lgkmcnt(0)" ::: "memory");  // prior buf reads retired
            stage(c + 1, b ^ 1);                                // in flight under compute
            asm volatile("s_waitcnt vmcnt(3)" ::: "memory");    // chunk c landed
        } else {
            asm volatile("s_waitcnt vmcnt(0)" ::: "memory");
        }

        const float* __restrict__ s = reinterpret_cast<const float*>(&sbuf[w][b][0]);
        const float* __restrict__ P = s + lane * 5;
        const float* __restrict__ T = s + WCHUNK * 5 + lane * 5;

        const float x = P[0];
        const float y = T[0];
        const float p0 = __fdividef(1.0f, 1.0f + __expf(-P[1]));
        const float p1 = __fdividef(1.0f, 1.0f + __expf(-P[2]));
        const float p2 = __fdividef(1.0f, 1.0f + __expf(-P[3]));
        const float p3 = __fdividef(1.0f, 1.0f + __expf(-P[4]));
        const float t0 = T[1], t1 = T[2], t2 = T[3], t3 = T[4];

        const float xp1 = fminf(p2, p0), xp2 = fmaxf(p2, p0);
        const float yp1 = fminf(p1, p3), yp2 = fmaxf(p1, p3);

        const float wv = xp2 - xp1;        // == |p2-p0|
        const float h  = yp2 - yp1;        // == |p3-p1|
        const float wt = t2 - t0;
        const float ht = t3 - t1;
        const float pred_area   = wv * h;
        const float target_area = wt * ht;

        const float x1 = fmaxf(xp1, t0), x2 = fminf(xp2, t2);
        const float y1 = fmaxf(yp1, t1), y2 = fminf(yp2, t3);

        float ov = (x2 - x1) * (y2 - y1);
        ov = (ov < 0.0f) ? 0.0f : ov;

        const float x1c = fminf(xp1, t0), x2c = fmaxf(xp2, t2);
        const float y1c = fminf(yp1, t1), y2c = fmaxf(yp2, t3);

        const float cw = x2c - x1c, ch = y2c - y1c;

        const float iou = __fdividef(ov, target_area + pred_area - ov);

        const float dx = 0.5f * ((xp1 + xp2) - (t0 + t2));
        const float dy = 0.5f * ((yp1 + yp2) - (t1 + t3));
        const float diag = cw * cw + ch * ch;
        const float center_part = __fdividef(dx * dx + dy * dy, diag);

        // width_part + height_part with one reciprocal:
        // (dwv/cw)^2 + (dhv/ht)^2 = ((dwv*ht)^2 + (dhv*cw)^2) / (cw*ht)^2
        const float dwv = wv - wt, dhv = h - ht;
        const float a = dwv * ht, bb = dhv * cw, d = cw * ht;
        const float wh_part = __fdividef(a * a + bb * bb, d * d);

        const float eiou = 1.0f - (iou - (center_part + wh_part));

        const float bce = fmaxf(x, 0.0f) - x * y
                        + __logf(1.0f + __expf(-fabsf(x)));

        acc += BCE_COEFF * bce + eiou;
    }

    // ---- block reduction ----
#pragma unroll
    for (int off = 32; off > 0; off >>= 1)
        acc += __shfl_down(acc, off);

    __syncthreads();                 // all LDS pipeline reads done
    float* sf = reinterpret_cast<float*>(&sbuf[0][0][0]);
    if (lane == 0) sf[w] = acc;
    __syncthreads();

    // ---- hierarchical fused tail: max 32 same-address RMWs per address ----
    // (round-7/9/10 lesson: same-address atomic RMW ~10 ns serialized; keep
    //  every chain <= 32-64 ops and it costs <1 us. No fences anywhere: all
    //  protocol ops are device-scope atomics at the coherent point; ordering
    //  within a block via s_waitcnt vmcnt(0).)
    if (t == 0) {
        const float bs = (sf[0] + sf[1]) + (sf[2] + sf[3]);
        unsigned* const wsu = reinterpret_cast<unsigned*>(wsf);
        float*    const subslot = wsf + (size_t)(blockIdx.x >> 5) * SLOT_STRIDE;
        unsigned* const subcnt  = wsu + SUBCNT_BASE + (size_t)(blockIdx.x >> 5) * SLOT_STRIDE;

        // Heal 0xAA poison: first op to touch each address is a CAS (no-op
        // after the first call; finishers reset state for later replays).
        atomicCAS(reinterpret_cast<unsigned*>(subslot), POISON, 0u);
        atomicCAS(subcnt, POISON, 0u);

        atomicAdd(subslot, bs);
        asm volatile("s_waitcnt vmcnt(0)" ::: "memory");   // add visible before count
        if (atomicAdd(subcnt, 1u) == 31u) {
            // group finisher: all 32 adds of this group have completed
            const float gsum = atomicAdd(subslot, 0.0f);   // coherent read
            atomicExch(subcnt, 0u);                        // reset for next replay
            atomicExch(subslot, 0.0f);

            float*    const superslot = wsf + SUPER_SLOT;
            unsigned* const supercnt  = wsu + SUPER_CNT;
            atomicCAS(reinterpret_cast<unsigned*>(superslot), POISON, 0u);
            atomicCAS(supercnt, POISON, 0u);

            atomicAdd(superslot, gsum);
            asm volatile("s_waitcnt vmcnt(0)" ::: "memory");
            if (atomicAdd(supercnt, 1u) == GROUPS - 1u) {
                const float total = atomicAdd(superslot, 0.0f);
                atomicExch(supercnt, 0u);
                atomicExch(superslot, 0.0f);
                out[0] = total * (1.0f / (float)N_BOXES);
            }
        }
    }
}

extern "C" void kernel_launch(void* const* d_in, const int* in_sizes, int n_in,
                              void* d_out, int out_size, void* d_ws, size_t ws_size,
                              hipStream_t stream) {
    const float* preds  = (const float*)d_in[0];
    const float* target = (const float*)d_in[1];
    float* wsf = (float*)d_ws;        // ~16.5 KB used; self-healing/self-resetting
    float* out = (float*)d_out;

    // Single dispatch, no memset nodes.
    eiou_main<<<NBLOCKS, BLOCK, 0, stream>>>(preds, target, wsf, out);
}